// Round 7
// baseline (155.972 us; speedup 1.0000x reference)
//
#include <hip/hip_runtime.h>
#include <math.h>

#define NPTS 100000
#define NVERTS 6890
#define NJ 24

#define TPB 256
#define PPT 4                           // points per thread
#define PPB (TPB * PPT)                 // 1024 points per block
#define NPB ((NPTS + PPB - 1) / PPB)    // 98 point-blocks
#define NCH 32                          // vertex chunks -> 98*32 = 3136 blocks
#define VCH ((NVERTS + NCH - 1) / NCH)  // 216 verts/chunk
#define VCH2 ((VCH + 1) / 2)            // 108 vertex PAIRS/chunk; LDS 2*108*16 = 3456 B

typedef float f32x2 __attribute__((ext_vector_type(2)));
union PK { float4 f4; f32x2 h[2]; };

// Forced VOP3P dual-f32 ops. Each 32-bit half executes an IEEE RTNE f32 op,
// bit-identical to the scalar v_mul/v_fma/v_add chain -> reference bit-match holds.
__device__ __forceinline__ f32x2 pk_mul(f32x2 a, f32x2 b) {
    f32x2 d;
    asm("v_pk_mul_f32 %0, %1, %2" : "=v"(d) : "v"(a), "v"(b));
    return d;
}
__device__ __forceinline__ f32x2 pk_fma(f32x2 a, f32x2 b, f32x2 c) {
    f32x2 d;
    asm("v_pk_fma_f32 %0, %1, %2, %3" : "=v"(d) : "v"(a), "v"(b), "v"(c));
    return d;
}
__device__ __forceinline__ f32x2 pk_add(f32x2 a, f32x2 b) {
    f32x2 d;
    asm("v_pk_add_f32 %0, %1, %2" : "=v"(d) : "v"(a), "v"(b));
    return d;
}

// ---------------- Kernel 1: f32 NN scan, v_pk_f32 dual-issue, bit-matching reference ----------------
// d2 = (xsq - 2*G) + vsq, G = ascending-k FMA dot (BLAS K=3), vsq = (vx^2+vy^2)+vz^2.
// Packed over 2 vertices per instruction; vert0-then-vert1 bookkeeping keeps np.argmin's
// first-index tie-break. LDS transposed-pair layout: A[j]={vx0,vx1,vy0,vy1},
// B[j]={vz0,vz1,vsq0,vsq1} -> pk operands are even-aligned subpairs of ds_read_b128.
// Partials merged via packed u64 atomicMin (f32bits(d2)<<32)|idx; OOB slots vsq=1e30.
__global__ __launch_bounds__(256, 6) void nn_kernel(
    const float* __restrict__ xyz,
    const float* __restrict__ verts,
    unsigned long long* __restrict__ best_ws)
{
#pragma clang fp contract(off)
    __shared__ float4 vldsA[VCH2];
    __shared__ float4 vldsB[VCH2];
    const int tid = threadIdx.x;
    const int vbase = blockIdx.y * VCH;

    for (int j = tid; j < VCH2; j += TPB) {
        const int v0 = vbase + 2 * j;
        const int v1 = v0 + 1;
        float x0 = 0.f, y0 = 0.f, z0 = 0.f, q0 = 1e30f;
        float x1 = 0.f, y1 = 0.f, z1 = 0.f, q1 = 1e30f;
        if (v0 < NVERTS) {
            x0 = verts[v0 * 3 + 0]; y0 = verts[v0 * 3 + 1]; z0 = verts[v0 * 3 + 2];
            q0 = (x0 * x0 + y0 * y0) + z0 * z0;
        }
        if (v1 < NVERTS) {
            x1 = verts[v1 * 3 + 0]; y1 = verts[v1 * 3 + 1]; z1 = verts[v1 * 3 + 2];
            q1 = (x1 * x1 + y1 * y1) + z1 * z1;
        }
        vldsA[j] = make_float4(x0, x1, y0, y1);
        vldsB[j] = make_float4(z0, z1, q0, q1);
    }
    __syncthreads();

    const int p0 = blockIdx.x * PPB + tid;
    f32x2 px2[PPT], py2[PPT], pz2[PPT], xs2[PPT];
    float bs[PPT];
    int bi[PPT];
    #pragma unroll
    for (int k = 0; k < PPT; ++k) {
        const int p = p0 + k * TPB;
        const int pc = (p < NPTS) ? p : (NPTS - 1);
        const float x = xyz[pc * 3 + 0];
        const float y = xyz[pc * 3 + 1];
        const float z = xyz[pc * 3 + 2];
        const float xs = (x * x + y * y) + z * z;
        px2[k] = (f32x2){x, x};  py2[k] = (f32x2){y, y};
        pz2[k] = (f32x2){z, z};  xs2[k] = (f32x2){xs, xs};
        bs[k] = 1e30f;
        bi[k] = 0;
    }
    const f32x2 m2 = {-2.0f, -2.0f};

    #pragma unroll 2
    for (int j = 0; j < VCH2; ++j) {
        PK A, B;
        A.f4 = vldsA[j];   // uniform-address broadcast ds_read_b128
        B.f4 = vldsB[j];
        const int vi0 = vbase + 2 * j;
        #pragma unroll
        for (int k = 0; k < PPT; ++k) {
            f32x2 g = pk_mul(px2[k], A.h[0]);        // rnd(x*vx) per half
            g = pk_fma(py2[k], A.h[1], g);           // ascending-k FMA chain
            g = pk_fma(pz2[k], B.h[0], g);
            f32x2 d = pk_fma(m2, g, xs2[k]);         // rnd(xsq - 2G), 2G exact
            d = pk_add(d, B.h[1]);                   // rnd(t + vsq)
            // vert0 then vert1: ascending index, first-index tie-break
            bi[k] = (d.x < bs[k]) ? vi0 : bi[k];
            bs[k] = fminf(bs[k], d.x);
            bi[k] = (d.y < bs[k]) ? (vi0 + 1) : bi[k];
            bs[k] = fminf(bs[k], d.y);
        }
    }

    #pragma unroll
    for (int k = 0; k < PPT; ++k) {
        const int p = p0 + k * TPB;
        if (p < NPTS) {
            const unsigned long long pk =
                ((unsigned long long)__float_as_uint(bs[k]) << 32) |
                (unsigned int)bi[k];
            atomicMin(&best_ws[p], pk);
        }
    }
}

// ---------------- Kernel 2: per-point skinning + quaternion + outputs ----------------
__global__ __launch_bounds__(256) void apply_kernel(
    const float* __restrict__ xyz,
    const float* __restrict__ rot,
    const float* __restrict__ sw,
    const float* __restrict__ tm,
    const unsigned long long* __restrict__ best_ws,
    float* __restrict__ out)
{
    __shared__ float tl[NJ * 16];
    const int tid = threadIdx.x;
    for (int i = tid; i < NJ * 16; i += 256) tl[i] = tm[i];
    __syncthreads();

    const int p = blockIdx.x * 256 + tid;
    if (p >= NPTS) return;

    const int vi = (int)(best_ws[p] & 0xFFFFFFFFull);
    const float4* w4 = reinterpret_cast<const float4*>(sw + (size_t)vi * NJ);

    float T[16];
    #pragma unroll
    for (int i = 0; i < 16; ++i) T[i] = 0.0f;

    #pragma unroll
    for (int jq = 0; jq < NJ / 4; ++jq) {
        const float4 wv = w4[jq];
        const float wj[4] = { wv.x, wv.y, wv.z, wv.w };
        #pragma unroll
        for (int k = 0; k < 4; ++k) {
            const int j = jq * 4 + k;
            #pragma unroll
            for (int i = 0; i < 16; ++i)
                T[i] = fmaf(wj[k], tl[j * 16 + i], T[i]);
        }
    }

    // quaternion -> rotation matrix
    const float4 q = reinterpret_cast<const float4*>(rot)[p];
    float qr = q.x, qx = q.y, qy = q.z, qz = q.w;
    const float inv = 1.0f / sqrtf(qr * qr + qx * qx + qy * qy + qz * qz);
    qr *= inv; qx *= inv; qy *= inv; qz *= inv;
    float R[9];
    R[0] = 1.0f - 2.0f * (qy * qy + qz * qz);
    R[1] = 2.0f * (qx * qy - qr * qz);
    R[2] = 2.0f * (qx * qz + qr * qy);
    R[3] = 2.0f * (qx * qy + qr * qz);
    R[4] = 1.0f - 2.0f * (qx * qx + qz * qz);
    R[5] = 2.0f * (qy * qz - qr * qx);
    R[6] = 2.0f * (qx * qz - qr * qy);
    R[7] = 2.0f * (qy * qz + qr * qx);
    R[8] = 1.0f - 2.0f * (qx * qx + qy * qy);

    const float x0 = xyz[p * 3 + 0];
    const float x1 = xyz[p * 3 + 1];
    const float x2 = xyz[p * 3 + 2];

    // x_bar: out[0 .. 300000)
    #pragma unroll
    for (int i = 0; i < 3; ++i) {
        out[p * 3 + i] = fmaf(T[i * 4 + 0], x0,
                          fmaf(T[i * 4 + 1], x1,
                           fmaf(T[i * 4 + 2], x2, T[i * 4 + 3])));
    }

    // rotation_bar: out[300000 .. 1200000), [p][i][k] = sum_j T[i*4+j]*R[j*3+k]
    float* rb = out + 300000 + (size_t)p * 9;
    #pragma unroll
    for (int i = 0; i < 3; ++i) {
        #pragma unroll
        for (int k = 0; k < 3; ++k) {
            rb[i * 3 + k] = fmaf(T[i * 4 + 0], R[0 * 3 + k],
                             fmaf(T[i * 4 + 1], R[1 * 3 + k],
                                  T[i * 4 + 2] * R[2 * 3 + k]));
        }
    }

    // T_fwd: out[1200000 .. 2800000)
    float* tb = out + 1200000 + (size_t)p * 16;
    #pragma unroll
    for (int i = 0; i < 16; ++i) tb[i] = T[i];
}

extern "C" void kernel_launch(void* const* d_in, const int* in_sizes, int n_in,
                              void* d_out, int out_size, void* d_ws, size_t ws_size,
                              hipStream_t stream) {
    const float* xyz   = (const float*)d_in[0];
    const float* rot   = (const float*)d_in[1];
    const float* verts = (const float*)d_in[2];
    const float* sw    = (const float*)d_in[3];
    const float* tm    = (const float*)d_in[4];
    float* out = (float*)d_out;

    unsigned long long* best_ws = (unsigned long long*)d_ws;  // NPTS packed (d2,idx)

    // init packed mins to 0xFFFF... (max u64) each call -- capture-safe async memset
    hipMemsetAsync(d_ws, 0xFF, NPTS * sizeof(unsigned long long), stream);

    dim3 grid(NPB, NCH);  // 98 x 32 = 3136 blocks
    nn_kernel<<<grid, TPB, 0, stream>>>(xyz, verts, best_ws);
    apply_kernel<<<(NPTS + 255) / 256, 256, 0, stream>>>(xyz, rot, sw, tm, best_ws, out);
}